// Round 3
// baseline (124.565 us; speedup 1.0000x reference)
//
#include <hip/hip_runtime.h>
#include <math.h>

#define HH 1024
#define WW 1024
#define PADK 15
#define RB 16
#define TPB 512
#define NPAIR 32           // 32-row band-pairs per image
#define EPSV 1e-5f
#define INV_K2 (1.0f / 961.0f)

__device__ __forceinline__ float lcn_px(float xv, float hs, float hq) {
    float mean = hs * INV_K2;
    float sq   = hq * INV_K2;
    float var  = sq - mean * mean;
    float sd   = sqrtf(fmaxf(var, EPSV));
    float nrm  = (xv - mean) * __builtin_amdgcn_rcpf(sd + EPSV);
    float enh  = 1.0f / (1.0f + __expf(-0.5f * nrm));
    return xv * 0.2f + enh * 0.8f;
}

__global__ __launch_bounds__(TPB, 8) void lcn_kernel(const float* __restrict__ x,
                                                     float* __restrict__ out) {
    // 8 waves/block. Waves 0-3: band A (rows r0..r0+15), waves 4-7: band B
    // (rows r0+16..r0+31). Within a band, wave quarter wq owns cols
    // wq*256..wq*256+255, 4 cols/lane. Per-wave private LDS regions
    // (16 halo | 256 owned | 16 halo, padded to 296). No __syncthreads:
    // all LDS traffic is wave-local; DS ops are in-order within a wave.
    __shared__ __align__(16) float sxl[8][296];
    __shared__ __align__(16) float sql[8][296];

    const int blk  = blockIdx.x;
    const int b    = blk >> 5;         // image
    const int pair = blk & 31;         // 32-row pair within image
    const int t    = threadIdx.x;
    const int w    = t >> 6;           // wave id 0..7
    const int l    = t & 63;           // lane
    const int band = w >> 2;           // 0 or 1
    const int wq   = w & 3;            // column quarter
    const int r0   = pair * 32 + band * RB;
    const int wc0  = wq * 256;
    const int c0   = wc0 + l * 4;

    float* __restrict__ sxw = sxl[w];
    float* __restrict__ sqw = sql[w];

    // halo assignment: lanes 0..3 -> left halo float4s, lanes 4..7 -> right
    int hcol = 0;
    bool hlane = (l < 8);
    if (l < 4)      hcol = wc0 - 16 + 4 * l;
    else if (l < 8) hcol = wc0 + 256 + 4 * (l - 4);
    const bool hvalid = hlane && (hcol >= 0) && (hcol < WW);
    const int  hidx   = (l < 4) ? 4 * l : 272 + 4 * (l - 4);

    const float* __restrict__ img  = x   + (size_t)b * HH * WW;
    float* __restrict__       oimg = out + (size_t)b * HH * WW;

    float4 s   = make_float4(0.f, 0.f, 0.f, 0.f);
    float4 s2  = make_float4(0.f, 0.f, 0.f, 0.f);
    float4 hs  = make_float4(0.f, 0.f, 0.f, 0.f);
    float4 hs2 = make_float4(0.f, 0.f, 0.f, 0.f);

    // --- init vertical sliding sums for output row r0 ---
    {
        int lo = r0 - PADK; if (lo < 0) lo = 0;
        int hi = r0 + PADK;                 // r0 <= 1008 -> hi <= 1023
        for (int r = lo; r <= hi; ++r) {
            const float* rowp = img + (size_t)r * WW;
            float4 v = *reinterpret_cast<const float4*>(rowp + c0);
            s.x  += v.x;       s.y  += v.y;       s.z  += v.z;       s.w  += v.w;
            s2.x += v.x * v.x; s2.y += v.y * v.y; s2.z += v.z * v.z; s2.w += v.w * v.w;
            if (hvalid) {
                float4 hv = *reinterpret_cast<const float4*>(rowp + hcol);
                hs.x  += hv.x;        hs.y  += hv.y;        hs.z  += hv.z;        hs.w  += hv.w;
                hs2.x += hv.x * hv.x; hs2.y += hv.y * hv.y; hs2.z += hv.z * hv.z; hs2.w += hv.w * hv.w;
            }
        }
    }

    for (int orow = r0; orow < r0 + RB; ++orow) {
        if (orow > r0) {
            const int radd = orow + PADK;
            const int rsub = orow - PADK - 1;
            if (radd < HH) {
                const float* rowp = img + (size_t)radd * WW;
                float4 v = *reinterpret_cast<const float4*>(rowp + c0);
                s.x  += v.x;       s.y  += v.y;       s.z  += v.z;       s.w  += v.w;
                s2.x += v.x * v.x; s2.y += v.y * v.y; s2.z += v.z * v.z; s2.w += v.w * v.w;
                if (hvalid) {
                    float4 hv = *reinterpret_cast<const float4*>(rowp + hcol);
                    hs.x  += hv.x;        hs.y  += hv.y;        hs.z  += hv.z;        hs.w  += hv.w;
                    hs2.x += hv.x * hv.x; hs2.y += hv.y * hv.y; hs2.z += hv.z * hv.z; hs2.w += hv.w * hv.w;
                }
            }
            if (rsub >= 0) {
                const float* rowp = img + (size_t)rsub * WW;
                float4 v = *reinterpret_cast<const float4*>(rowp + c0);
                s.x  -= v.x;       s.y  -= v.y;       s.z  -= v.z;       s.w  -= v.w;
                s2.x -= v.x * v.x; s2.y -= v.y * v.y; s2.z -= v.z * v.z; s2.w -= v.w * v.w;
                if (hvalid) {
                    float4 hv = *reinterpret_cast<const float4*>(rowp + hcol);
                    hs.x  -= hv.x;        hs.y  -= hv.y;        hs.z  -= hv.z;        hs.w  -= hv.w;
                    hs2.x -= hv.x * hv.x; hs2.y -= hv.y * hv.y; hs2.z -= hv.z * hv.z; hs2.w -= hv.w * hv.w;
                }
            }
        }

        // write this wave's vertical sums (owned + halo) to its LDS region
        *reinterpret_cast<float4*>(sxw + 16 + 4 * l) = s;
        *reinterpret_cast<float4*>(sqw + 16 + 4 * l) = s2;
        if (hlane) {
            *reinterpret_cast<float4*>(sxw + hidx) = hs;   // zeros when !hvalid
            *reinterpret_cast<float4*>(sqw + hidx) = hs2;
        }
        // no barrier: DS ops are in-order within a wave

        // --- horizontal 31-window sums for 4 columns ---
        float wx[36], wq_[36];
        #pragma unroll
        for (int m = 0; m < 9; ++m) {
            float4 a = *reinterpret_cast<const float4*>(sxw + 4 * l + 4 * m);
            wx[4*m+0] = a.x; wx[4*m+1] = a.y; wx[4*m+2] = a.z; wx[4*m+3] = a.w;
            float4 c = *reinterpret_cast<const float4*>(sqw + 4 * l + 4 * m);
            wq_[4*m+0] = c.x; wq_[4*m+1] = c.y; wq_[4*m+2] = c.z; wq_[4*m+3] = c.w;
        }

        float a0 = 0.f, a1 = 0.f, a2 = 0.f, a3 = 0.f;
        float b0 = 0.f, b1 = 0.f, b2 = 0.f, b3 = 0.f;
        #pragma unroll
        for (int j = 4; j < 32; j += 4) {
            a0 += wx[j];    a1 += wx[j+1];  a2 += wx[j+2];  a3 += wx[j+3];
            b0 += wq_[j];   b1 += wq_[j+1]; b2 += wq_[j+2]; b3 += wq_[j+3];
        }
        float base  = (a0 + a1) + (a2 + a3);
        float base2 = (b0 + b1) + (b2 + b3);

        float hs0 = base  + wx[1]   + wx[2]   + wx[3];
        float hs1 = base  + wx[2]   + wx[3]   + wx[32];
        float hs2_ = base + wx[3]   + wx[32]  + wx[33];
        float hs3 = base  + wx[32]  + wx[33]  + wx[34];
        float hq0 = base2 + wq_[1]  + wq_[2]  + wq_[3];
        float hq1 = base2 + wq_[2]  + wq_[3]  + wq_[32];
        float hq2 = base2 + wq_[3]  + wq_[32] + wq_[33];
        float hq3 = base2 + wq_[32] + wq_[33] + wq_[34];

        float4 xc = *reinterpret_cast<const float4*>(img + (size_t)orow * WW + c0);

        float4 ro;
        ro.x = lcn_px(xc.x, hs0, hq0);
        ro.y = lcn_px(xc.y, hs1, hq1);
        ro.z = lcn_px(xc.z, hs2_, hq2);
        ro.w = lcn_px(xc.w, hs3, hq3);
        *reinterpret_cast<float4*>(oimg + (size_t)orow * WW + c0) = ro;
    }
}

extern "C" void kernel_launch(void* const* d_in, const int* in_sizes, int n_in,
                              void* d_out, int out_size, void* d_ws, size_t ws_size,
                              hipStream_t stream) {
    const float* xin = (const float*)d_in[0];
    float* out = (float*)d_out;
    const int B = in_sizes[0] / (HH * WW);   // 32
    dim3 grid(B * NPAIR);                    // 1024 blocks x 8 waves = 32 waves/CU
    dim3 block(TPB);
    hipLaunchKernelGGL(lcn_kernel, grid, block, 0, stream, xin, out);
}

// Round 4
// 121.268 us; speedup vs baseline: 1.0272x; 1.0272x over previous
//
#include <hip/hip_runtime.h>
#include <math.h>

#define HH 1024
#define WW 1024
#define PADK 15
#define RB 16
#define TPB 512
#define NPAIR 32           // 32-row band-pairs per image
#define EPSV 1e-5f
#define INV_K2 (1.0f / 961.0f)

__global__ __launch_bounds__(TPB) void lcn_kernel(const float* __restrict__ x,
                                                  float* __restrict__ out) {
    // 8 waves/block. Waves 0-3: band A (rows r0..r0+15), waves 4-7: band B
    // (rows r0+16..r0+31). Within a band, wave quarter wq owns cols
    // wq*256..wq*256+255, 4 cols/lane. Per-wave private LDS regions
    // (16 halo | 256 owned | 16 halo, padded to 296). No __syncthreads:
    // all LDS traffic is wave-local; DS ops are in-order within a wave.
    // Horizontal pass STREAMS the base sum (keeps only edge float4s) to
    // stay under 64 VGPR -- round 3 showed forced staging spills to scratch.
    __shared__ __align__(16) float sxl[8][296];
    __shared__ __align__(16) float sql[8][296];

    const int blk  = blockIdx.x;
    const int b    = blk >> 5;         // image
    const int pair = blk & 31;         // 32-row pair within image
    const int t    = threadIdx.x;
    const int w    = t >> 6;           // wave id 0..7
    const int l    = t & 63;           // lane
    const int band = w >> 2;           // 0 or 1
    const int wq   = w & 3;            // column quarter
    const int r0   = pair * 32 + band * RB;
    const int wc0  = wq * 256;
    const int c0   = wc0 + l * 4;

    float* __restrict__ sxw = sxl[w];
    float* __restrict__ sqw = sql[w];

    // halo assignment: lanes 0..3 -> left halo float4s, lanes 4..7 -> right
    int hcol = 0;
    bool hlane = (l < 8);
    if (l < 4)      hcol = wc0 - 16 + 4 * l;
    else if (l < 8) hcol = wc0 + 256 + 4 * (l - 4);
    const bool hvalid = hlane && (hcol >= 0) && (hcol < WW);
    const int  hidx   = (l < 4) ? 4 * l : 272 + 4 * (l - 4);

    const float* __restrict__ img  = x   + (size_t)b * HH * WW;
    float* __restrict__       oimg = out + (size_t)b * HH * WW;

    float4 s   = make_float4(0.f, 0.f, 0.f, 0.f);
    float4 s2  = make_float4(0.f, 0.f, 0.f, 0.f);
    float4 hs  = make_float4(0.f, 0.f, 0.f, 0.f);
    float4 hs2 = make_float4(0.f, 0.f, 0.f, 0.f);

    // --- init vertical sliding sums for output row r0 ---
    {
        int lo = r0 - PADK; if (lo < 0) lo = 0;
        int hi = r0 + PADK;                 // r0 <= 1008 -> hi <= 1023
        for (int r = lo; r <= hi; ++r) {
            const float* rowp = img + (size_t)r * WW;
            float4 v = *reinterpret_cast<const float4*>(rowp + c0);
            s.x  += v.x;       s.y  += v.y;       s.z  += v.z;       s.w  += v.w;
            s2.x += v.x * v.x; s2.y += v.y * v.y; s2.z += v.z * v.z; s2.w += v.w * v.w;
            if (hvalid) {
                float4 hv = *reinterpret_cast<const float4*>(rowp + hcol);
                hs.x  += hv.x;        hs.y  += hv.y;        hs.z  += hv.z;        hs.w  += hv.w;
                hs2.x += hv.x * hv.x; hs2.y += hv.y * hv.y; hs2.z += hv.z * hv.z; hs2.w += hv.w * hv.w;
            }
        }
    }

    for (int orow = r0; orow < r0 + RB; ++orow) {
        if (orow > r0) {
            const int radd = orow + PADK;
            const int rsub = orow - PADK - 1;
            if (radd < HH) {
                const float* rowp = img + (size_t)radd * WW;
                float4 v = *reinterpret_cast<const float4*>(rowp + c0);
                s.x  += v.x;       s.y  += v.y;       s.z  += v.z;       s.w  += v.w;
                s2.x += v.x * v.x; s2.y += v.y * v.y; s2.z += v.z * v.z; s2.w += v.w * v.w;
                if (hvalid) {
                    float4 hv = *reinterpret_cast<const float4*>(rowp + hcol);
                    hs.x  += hv.x;        hs.y  += hv.y;        hs.z  += hv.z;        hs.w  += hv.w;
                    hs2.x += hv.x * hv.x; hs2.y += hv.y * hv.y; hs2.z += hv.z * hv.z; hs2.w += hv.w * hv.w;
                }
            }
            if (rsub >= 0) {
                const float* rowp = img + (size_t)rsub * WW;
                float4 v = *reinterpret_cast<const float4*>(rowp + c0);
                s.x  -= v.x;       s.y  -= v.y;       s.z  -= v.z;       s.w  -= v.w;
                s2.x -= v.x * v.x; s2.y -= v.y * v.y; s2.z -= v.z * v.z; s2.w -= v.w * v.w;
                if (hvalid) {
                    float4 hv = *reinterpret_cast<const float4*>(rowp + hcol);
                    hs.x  -= hv.x;        hs.y  -= hv.y;        hs.z  -= hv.z;        hs.w  -= hv.w;
                    hs2.x -= hv.x * hv.x; hs2.y -= hv.y * hv.y; hs2.z -= hv.z * hv.z; hs2.w -= hv.w * hv.w;
                }
            }
        }

        // write this wave's vertical sums (owned + halo) to its LDS region
        *reinterpret_cast<float4*>(sxw + 16 + 4 * l) = s;
        *reinterpret_cast<float4*>(sqw + 16 + 4 * l) = s2;
        if (hlane) {
            *reinterpret_cast<float4*>(sxw + hidx) = hs;   // zeros when !hvalid
            *reinterpret_cast<float4*>(sqw + hidx) = hs2;
        }
        // no barrier: DS ops are in-order within a wave

        // --- horizontal 31-window sums, streamed (low register pressure) ---
        // window for owned col q: LDS elems (4l + q+1 .. 4l + q+31)
        // base = elems 4..31 (R1..R7 complete); edges come from R0 / R8.
        float mean0, mean1, mean2, mean3;
        {
            float4 r0v = *reinterpret_cast<const float4*>(sxw + 4 * l);
            float b0 = 0.f, b1 = 0.f;
            #pragma unroll
            for (int m = 1; m < 8; ++m) {
                float4 v = *reinterpret_cast<const float4*>(sxw + 4 * l + 4 * m);
                b0 += (v.x + v.y);
                b1 += (v.z + v.w);
            }
            float4 r8v = *reinterpret_cast<const float4*>(sxw + 4 * l + 32);
            float base = b0 + b1;
            mean0 = (base + ((r0v.y + r0v.z) + r0v.w)) * INV_K2;
            mean1 = (base + ((r0v.z + r0v.w) + r8v.x)) * INV_K2;
            mean2 = (base + ((r0v.w + r8v.x) + r8v.y)) * INV_K2;
            mean3 = (base + ((r8v.x + r8v.y) + r8v.z)) * INV_K2;
        }
        float sq0, sq1, sq2, sq3;
        {
            float4 r0v = *reinterpret_cast<const float4*>(sqw + 4 * l);
            float b0 = 0.f, b1 = 0.f;
            #pragma unroll
            for (int m = 1; m < 8; ++m) {
                float4 v = *reinterpret_cast<const float4*>(sqw + 4 * l + 4 * m);
                b0 += (v.x + v.y);
                b1 += (v.z + v.w);
            }
            float4 r8v = *reinterpret_cast<const float4*>(sqw + 4 * l + 32);
            float base = b0 + b1;
            sq0 = (base + ((r0v.y + r0v.z) + r0v.w)) * INV_K2;
            sq1 = (base + ((r0v.z + r0v.w) + r8v.x)) * INV_K2;
            sq2 = (base + ((r0v.w + r8v.x) + r8v.y)) * INV_K2;
            sq3 = (base + ((r8v.x + r8v.y) + r8v.z)) * INV_K2;
        }

        float4 xc = *reinterpret_cast<const float4*>(img + (size_t)orow * WW + c0);

        float4 ro;
        {
            float sd  = sqrtf(fmaxf(sq0 - mean0 * mean0, EPSV));
            float nrm = (xc.x - mean0) * __builtin_amdgcn_rcpf(sd + EPSV);
            ro.x = xc.x * 0.2f + 0.8f / (1.0f + __expf(-0.5f * nrm));
        }
        {
            float sd  = sqrtf(fmaxf(sq1 - mean1 * mean1, EPSV));
            float nrm = (xc.y - mean1) * __builtin_amdgcn_rcpf(sd + EPSV);
            ro.y = xc.y * 0.2f + 0.8f / (1.0f + __expf(-0.5f * nrm));
        }
        {
            float sd  = sqrtf(fmaxf(sq2 - mean2 * mean2, EPSV));
            float nrm = (xc.z - mean2) * __builtin_amdgcn_rcpf(sd + EPSV);
            ro.z = xc.z * 0.2f + 0.8f / (1.0f + __expf(-0.5f * nrm));
        }
        {
            float sd  = sqrtf(fmaxf(sq3 - mean3 * mean3, EPSV));
            float nrm = (xc.w - mean3) * __builtin_amdgcn_rcpf(sd + EPSV);
            ro.w = xc.w * 0.2f + 0.8f / (1.0f + __expf(-0.5f * nrm));
        }
        *reinterpret_cast<float4*>(oimg + (size_t)orow * WW + c0) = ro;
    }
}

extern "C" void kernel_launch(void* const* d_in, const int* in_sizes, int n_in,
                              void* d_out, int out_size, void* d_ws, size_t ws_size,
                              hipStream_t stream) {
    const float* xin = (const float*)d_in[0];
    float* out = (float*)d_out;
    const int B = in_sizes[0] / (HH * WW);   // 32
    dim3 grid(B * NPAIR);                    // 1024 blocks x 8 waves
    dim3 block(TPB);
    hipLaunchKernelGGL(lcn_kernel, grid, block, 0, stream, xin, out);
}